// Round 5
// baseline (82.243 us; speedup 1.0000x reference)
//
#include <hip/hip_runtime.h>

// SSF_Extractor: out = x * resize_bilinear_ac(local_unbiased_var_5x5(x), 256, 256)
// x: (8, 64, 256, 256) fp32.
//
// Wave-synchronous design: one 64-lane wave owns one 16-output-row full-width
// strip; lane l owns columns 4l..4l+3. Vertical 5-row sliding sums in
// registers; horizontal 5-tap via right-neighbor exchange through LDS (b128,
// in-order within the wave -> NO barriers); variance rows in a 2-row LDS ring;
// output rows emitted eagerly as their var rows appear, with the emit x-row
// prefetched one row ahead. 16-row strips double the grid (2048 blocks = 8
// blocks/CU = 32 waves/CU) to hide the serial LDS/load latency chain.

namespace {

constexpr int W = 256;
constexpr int STRIP = 16;
#define SC (251.0f / 255.0f)  // align_corners scale (h-1)/(H-1)

__global__ __launch_bounds__(256, 8) void ssf_wave(const float* __restrict__ x,
                                                   float* __restrict__ out) {
  __shared__ float lds[4][1024];  // per wave: sbuf[256] | qbuf[256] | ring[2][256]

  const int tid = threadIdx.x;
  const int lane = tid & 63;
  const int wv = tid >> 6;

  float* const sbuf = &lds[wv][0];
  float* const qbuf = &lds[wv][256];
  float* const ring = &lds[wv][512];

  // XCD-chunked block swizzle (2048 blocks, 8 XCDs, 2048%8==0 -> bijective).
  const int b = blockIdx.x;
  const int bs = (b & 7) * 256 + (b >> 3);
  const int sid = __builtin_amdgcn_readfirstlane(bs * 4 + wv);
  const int img = sid >> 4;                  // 0..511 (16 strips per image)
  const int y0 = (sid & 15) * STRIP;         // strip base output row

  const float* const xi = x + (size_t)img * (W * W);
  float* const oi = out + (size_t)img * (W * W);

  const int vymin = (y0 * 251) / 255;
  int vymax = ((y0 + STRIP - 1) * 251) / 255 + 1;
  if (vymax > 251) vymax = 251;
  const int VR = vymax - vymin + 1;  // 16 or 17, wave-uniform
  // x rows needed: vymin .. vymax+4 (<= 255 always; no clamping needed).

  const int c0 = lane * 4;

  // ---- Per-lane horizontal bilinear constants ----
  // q0 = x0i(c0); for col c0+i: x0i - q0 in {i-1, i} (i=0 -> 0), x1i - q0 in {i, i+1}.
  const int q0 = (int)floorf((float)c0 * SC);
  float wxv[4];
  bool selA[4], selB[4];
#pragma unroll
  for (int i = 0; i < 4; ++i) {
    float xs = (float)(c0 + i) * SC;
    float x0f = floorf(xs);
    int x0 = (int)x0f;
    wxv[i] = xs - x0f;
    selA[i] = (x0 - q0) == i;
    int x1 = x0 + 1;
    if (x1 > 251) x1 = 251;
    selB[i] = (x1 - q0) == (i + 1);
  }

  // First emit row prefetch (consumed at v ~= 1).
  float4 xe = *(const float4*)(xi + (size_t)y0 * W + c0);

  // ---- Init vertical partial sums over x rows vymin..vymin+3 ----
  const float* const xrow = xi + (size_t)vymin * W + c0;
  float sacc[4] = {0.f, 0.f, 0.f, 0.f};
  float qacc[4] = {0.f, 0.f, 0.f, 0.f};
  float4 xo = {0.f, 0.f, 0.f, 0.f}, xn;
#pragma unroll
  for (int r = 0; r < 4; ++r) {
    float4 xv = *(const float4*)(xrow + r * W);
    float xa[4] = {xv.x, xv.y, xv.z, xv.w};
#pragma unroll
    for (int i = 0; i < 4; ++i) {
      sacc[i] += xa[i];
      qacc[i] = fmaf(xa[i], xa[i], qacc[i]);
    }
    if (r == 0) xo = xv;
  }
  xn = *(const float4*)(xrow + 4 * W);

  int jn = 0, cur = -1000;
  float vl[5], vh[5];
#pragma unroll
  for (int i = 0; i < 5; ++i) { vl[i] = 0.f; vh[i] = 0.f; }

  for (int v = 0; v < VR; ++v) {
    // Prefetch next iteration's two x rows (L1/L2/L3-warm).
    float4 xn2, xo2;
    if (v + 1 < VR) {
      xn2 = *(const float4*)(xrow + (size_t)(v + 5) * W);
      xo2 = *(const float4*)(xrow + (size_t)(v + 1) * W);
    }
    float xna[4] = {xn.x, xn.y, xn.z, xn.w};
    float xoa[4] = {xo.x, xo.y, xo.z, xo.w};
    float s5[4], q5[4];
#pragma unroll
    for (int i = 0; i < 4; ++i) {
      s5[i] = sacc[i] + xna[i];
      q5[i] = fmaf(xna[i], xna[i], qacc[i]);
    }
    // Export own 4 column-sums; import right neighbor's (in-order DS, no barrier).
    *(float4*)(sbuf + c0) = make_float4(s5[0], s5[1], s5[2], s5[3]);
    *(float4*)(qbuf + c0) = make_float4(q5[0], q5[1], q5[2], q5[3]);
    const int nb = (lane < 63) ? (c0 + 4) : c0;  // lane 63 computes unused junk
    float4 ns = *(const float4*)(sbuf + nb);
    float4 nq = *(const float4*)(qbuf + nb);
    // Horizontal 5-tap (sliding) + unbiased variance for var cols c0..c0+3.
    float hs0 = ((s5[0] + s5[1]) + (s5[2] + s5[3])) + ns.x;
    float hq0 = ((q5[0] + q5[1]) + (q5[2] + q5[3])) + nq.x;
    float hs1 = hs0 - s5[0] + ns.y;
    float hq1 = hq0 - q5[0] + nq.y;
    float hs2 = hs1 - s5[1] + ns.z;
    float hq2 = hq1 - q5[1] + nq.z;
    float hs3 = hs2 - s5[2] + ns.w;
    float hq3 = hq2 - q5[2] + nq.w;
    float4 vr4;
    vr4.x = (hq0 - hs0 * hs0 * (1.0f / 25.0f)) * (1.0f / 24.0f);
    vr4.y = (hq1 - hs1 * hs1 * (1.0f / 25.0f)) * (1.0f / 24.0f);
    vr4.z = (hq2 - hs2 * hs2 * (1.0f / 25.0f)) * (1.0f / 24.0f);
    vr4.w = (hq3 - hs3 * hs3 * (1.0f / 25.0f)) * (1.0f / 24.0f);
    *(float4*)(ring + (v & 1) * 256 + c0) = vr4;
    // Slide the vertical window down one row.
#pragma unroll
    for (int i = 0; i < 4; ++i) {
      sacc[i] = s5[i] - xoa[i];
      qacc[i] = fmaf(-xoa[i], xoa[i], q5[i]);
    }
    xn = xn2;
    xo = xo2;

    // ---- Emit output rows whose two var rows are now in the ring ----
    while (jn < STRIP) {
      int gy = y0 + jn;
      int vy = (gy * 251) / 255;  // exact integer floor
      int vy1 = vy + 1;
      if (vy1 > 251) vy1 = 251;
      if (vy1 - vymin > v) break;  // not ready yet (wave-uniform)
      float4 xv = xe;
      if (jn + 1 < STRIP)          // prefetch next emit row (hides load latency)
        xe = *(const float4*)(xi + (size_t)(gy + 1) * W + c0);
      float ys = (float)gy * SC;
      float wy = ys - (float)vy;   // may be ~1e-5 off at clamp row; harmless
      int vrr = vy - vymin;
      if (vrr != cur) {
        if (vrr == cur + 1) {
#pragma unroll
          for (int i = 0; i < 5; ++i) vl[i] = vh[i];  // row-carry reuse
        } else {
          const float* rl = ring + (vrr & 1) * 256 + q0;
#pragma unroll
          for (int i = 0; i < 5; ++i) vl[i] = rl[i];
        }
        if (vy >= 251) {
#pragma unroll
          for (int i = 0; i < 5; ++i) vh[i] = vl[i];  // bottom clamp
        } else {
          const float* rh = ring + ((vrr + 1) & 1) * 256 + q0;
#pragma unroll
          for (int i = 0; i < 5; ++i) vh[i] = rh[i];
        }
        cur = vrr;
      }
      float xa2[4] = {xv.x, xv.y, xv.z, xv.w};
      float omwy = 1.0f - wy;
      float res[4];
#pragma unroll
      for (int i = 0; i < 4; ++i) {
        float a00 = (i == 0) ? vl[0] : (selA[i] ? vl[i] : vl[i - 1]);
        float a10 = (i == 0) ? vh[0] : (selA[i] ? vh[i] : vh[i - 1]);
        float a01 = selB[i] ? vl[i + 1] : vl[i];
        float a11 = selB[i] ? vh[i + 1] : vh[i];
        // Reference order: rows (wy) first, then cols (wx).
        float left = a00 * omwy + a10 * wy;
        float right = a01 * omwy + a11 * wy;
        res[i] = (left * (1.0f - wxv[i]) + right * wxv[i]) * xa2[i];
      }
      *(float4*)(oi + (size_t)gy * W + c0) =
          make_float4(res[0], res[1], res[2], res[3]);
      ++jn;
    }
  }
}

}  // namespace

extern "C" void kernel_launch(void* const* d_in, const int* in_sizes, int n_in,
                              void* d_out, int out_size, void* d_ws, size_t ws_size,
                              hipStream_t stream) {
  const float* x = (const float*)d_in[0];
  float* out = (float*)d_out;
  // 8192 strips (512 images x 16 strips), 4 waves (strips) per 256-thread block.
  ssf_wave<<<dim3(2048), dim3(256), 0, stream>>>(x, out);
}

// Round 6
// 61.405 us; speedup vs baseline: 1.3394x; 1.3394x over previous
//
#include <hip/hip_runtime.h>

// SSF_Extractor: out = x * resize_bilinear_ac(local_unbiased_var_5x5(x), 256, 256)
// x: (8, 64, 256, 256) fp32.
//
// Wave-synchronous, fully-static pipeline: one 64-lane wave owns one
// 32-output-row full-width strip; lane l owns columns 4l..4l+3.
// Fixed 33-iteration loop; iteration v computes var row v (guarded, uniform)
// into a depth-4 LDS ring and emits exactly one output row (j = v-1).
// Readiness proof: rh(j) <= j+1 and rl(j) >= v-2, so a depth-4 ring suffices
// and one-emit-per-iter never reads an unwritten row. All global loads are
// prefetched one iteration ahead with clamped indices -> no dynamic control
// flow, compiler can use counted vmcnt waits instead of draining.

namespace {

constexpr int W = 256;
constexpr int STRIP = 32;
#define SC (251.0f / 255.0f)  // align_corners scale (h-1)/(H-1)

__global__ __launch_bounds__(256, 4) void ssf_wave(const float* __restrict__ x,
                                                   float* __restrict__ out) {
  __shared__ float lds[4][1536];  // per wave: sbuf[256] | qbuf[256] | ring[4][256]

  const int tid = threadIdx.x;
  const int lane = tid & 63;
  const int wv = tid >> 6;

  float* const sbuf = &lds[wv][0];
  float* const qbuf = &lds[wv][256];
  float* const ring = &lds[wv][512];

  // XCD-chunked block swizzle (1024 blocks, 8 XCDs -> bijective).
  const int b = blockIdx.x;
  const int bs = (b & 7) * 128 + (b >> 3);
  const int sid = __builtin_amdgcn_readfirstlane(bs * 4 + wv);
  const int img = sid >> 3;                // 0..511
  const int y0 = (sid & 7) * STRIP;        // strip base output row

  const float* const xi = x + (size_t)img * (W * W);
  float* const oi = out + (size_t)img * (W * W);

  const int vymin = (y0 * 251) / 255;
  int vymax = ((y0 + STRIP - 1) * 251) / 255 + 1;
  if (vymax > 251) vymax = 251;
  const int VR = vymax - vymin + 1;  // 32 or 33, wave-uniform
  const int rmax = VR + 3;           // last needed relative x row (= vymax+4-vymin)

  const int c0 = lane * 4;

  // ---- Per-lane horizontal bilinear constants ----
  const int q0 = (int)floorf((float)c0 * SC);
  float wxv[4];
  bool selA[4], selB[4];
#pragma unroll
  for (int i = 0; i < 4; ++i) {
    float xs = (float)(c0 + i) * SC;
    float x0f = floorf(xs);
    int x0i = (int)x0f;
    wxv[i] = xs - x0f;
    selA[i] = (x0i - q0) == i;
    int x1i = x0i + 1;
    if (x1i > 251) x1i = 251;
    selB[i] = (x1i - q0) == (i + 1);
  }

  const float* const xrow = xi + (size_t)vymin * W + c0;

  // ---- Init: vertical partial sums over relative rows 0..3 ----
  float sacc[4] = {0.f, 0.f, 0.f, 0.f};
  float qacc[4] = {0.f, 0.f, 0.f, 0.f};
  float4 xo, xn, xe;
  {
    float4 rv[4];
#pragma unroll
    for (int r = 0; r < 4; ++r) rv[r] = *(const float4*)(xrow + r * W);
    xn = *(const float4*)(xrow + 4 * W);
    xe = *(const float4*)(xi + (size_t)y0 * W + c0);  // emit row for v=1
#pragma unroll
    for (int r = 0; r < 4; ++r) {
      float a[4] = {rv[r].x, rv[r].y, rv[r].z, rv[r].w};
#pragma unroll
      for (int i = 0; i < 4; ++i) {
        sacc[i] += a[i];
        qacc[i] = fmaf(a[i], a[i], qacc[i]);
      }
    }
    xo = rv[0];
  }

  int cur = -1000;
  float vl[5] = {0.f, 0.f, 0.f, 0.f, 0.f};
  float vh[5] = {0.f, 0.f, 0.f, 0.f, 0.f};

  for (int v = 0; v <= STRIP; ++v) {  // fixed 33 iterations
    // ---- Prefetch next iteration's inputs (clamped indices, branchless) ----
    int rn = v + 5;
    if (rn > rmax) rn = rmax;                 // xn for iter v+1 (rel row v+5)
    float4 xn_n = *(const float4*)(xrow + (size_t)rn * W);
    int ro = v + 1;
    if (ro > STRIP) ro = STRIP;               // xo for iter v+1 (rel row v+1)
    float4 xo_n = *(const float4*)(xrow + (size_t)ro * W);
    int re = v;
    if (re > STRIP - 1) re = STRIP - 1;       // emit row for iter v+1 (gy=y0+v)
    float4 xe_n = *(const float4*)(xi + (size_t)(y0 + re) * W + c0);

    // ---- Var row v (wave-uniform guard; only skipped at v=32 when VR=32) ----
    if (v < VR) {
      float xna[4] = {xn.x, xn.y, xn.z, xn.w};
      float xoa[4] = {xo.x, xo.y, xo.z, xo.w};
      float s5[4], q5[4];
#pragma unroll
      for (int i = 0; i < 4; ++i) {
        s5[i] = sacc[i] + xna[i];
        q5[i] = fmaf(xna[i], xna[i], qacc[i]);
      }
      // Right-neighbor exchange (in-order DS within the wave -> no barrier).
      *(float4*)(sbuf + c0) = make_float4(s5[0], s5[1], s5[2], s5[3]);
      *(float4*)(qbuf + c0) = make_float4(q5[0], q5[1], q5[2], q5[3]);
      const int nb = (lane < 63) ? (c0 + 4) : c0;  // lane 63: unused junk
      float4 ns = *(const float4*)(sbuf + nb);
      float4 nq = *(const float4*)(qbuf + nb);
      float hs0 = ((s5[0] + s5[1]) + (s5[2] + s5[3])) + ns.x;
      float hq0 = ((q5[0] + q5[1]) + (q5[2] + q5[3])) + nq.x;
      float hs1 = hs0 - s5[0] + ns.y;
      float hq1 = hq0 - q5[0] + nq.y;
      float hs2 = hs1 - s5[1] + ns.z;
      float hq2 = hq1 - q5[1] + nq.z;
      float hs3 = hs2 - s5[2] + ns.w;
      float hq3 = hq2 - q5[2] + nq.w;
      float4 vr4;
      vr4.x = (hq0 - hs0 * hs0 * (1.0f / 25.0f)) * (1.0f / 24.0f);
      vr4.y = (hq1 - hs1 * hs1 * (1.0f / 25.0f)) * (1.0f / 24.0f);
      vr4.z = (hq2 - hs2 * hs2 * (1.0f / 25.0f)) * (1.0f / 24.0f);
      vr4.w = (hq3 - hs3 * hs3 * (1.0f / 25.0f)) * (1.0f / 24.0f);
      *(float4*)(ring + (v & 3) * 256 + c0) = vr4;
      // Slide vertical window.
#pragma unroll
      for (int i = 0; i < 4; ++i) {
        sacc[i] = s5[i] - xoa[i];
        qacc[i] = fmaf(-xoa[i], xoa[i], q5[i]);
      }
    }

    // ---- Emit output row j = v-1 (exactly one per iteration) ----
    if (v >= 1) {
      const int gy = y0 + v - 1;
      const int vy = (gy * 251) / 255;  // exact integer floor
      const int rl = vy - vymin;        // in [v-2, v], in depth-4 ring
      float ys = (float)gy * SC;
      float wy = ys - (float)vy;
      if (rl != cur) {  // wave-uniform branch
        if (rl == cur + 1) {
#pragma unroll
          for (int i = 0; i < 5; ++i) vl[i] = vh[i];  // row-carry reuse
        } else {
          const float* rp = ring + (rl & 3) * 256 + q0;  // first emit only
#pragma unroll
          for (int i = 0; i < 5; ++i) vl[i] = rp[i];
        }
        if (vy >= 251) {
#pragma unroll
          for (int i = 0; i < 5; ++i) vh[i] = vl[i];  // bottom clamp
        } else {
          const float* rp = ring + ((rl + 1) & 3) * 256 + q0;
#pragma unroll
          for (int i = 0; i < 5; ++i) vh[i] = rp[i];
        }
        cur = rl;
      }
      float xa[4] = {xe.x, xe.y, xe.z, xe.w};
      float omwy = 1.0f - wy;
      float res[4];
#pragma unroll
      for (int i = 0; i < 4; ++i) {
        float a00 = (i == 0) ? vl[0] : (selA[i] ? vl[i] : vl[i - 1]);
        float a10 = (i == 0) ? vh[0] : (selA[i] ? vh[i] : vh[i - 1]);
        float a01 = selB[i] ? vl[i + 1] : vl[i];
        float a11 = selB[i] ? vh[i + 1] : vh[i];
        // Reference order: rows (wy) first, then cols (wx).
        float left = a00 * omwy + a10 * wy;
        float right = a01 * omwy + a11 * wy;
        res[i] = (left * (1.0f - wxv[i]) + right * wxv[i]) * xa[i];
      }
      *(float4*)(oi + (size_t)gy * W + c0) =
          make_float4(res[0], res[1], res[2], res[3]);
    }

    xn = xn_n;
    xo = xo_n;
    xe = xe_n;
  }
}

}  // namespace

extern "C" void kernel_launch(void* const* d_in, const int* in_sizes, int n_in,
                              void* d_out, int out_size, void* d_ws, size_t ws_size,
                              hipStream_t stream) {
  const float* x = (const float*)d_in[0];
  float* out = (float*)d_out;
  // 4096 strips (512 images x 8 strips), 4 waves (strips) per 256-thread block.
  ssf_wave<<<dim3(1024), dim3(256), 0, stream>>>(x, out);
}

// Round 7
// 48.439 us; speedup vs baseline: 1.6979x; 1.2677x over previous
//
#include <hip/hip_runtime.h>

// SSF_Extractor: out = x * resize_bilinear_ac(local_unbiased_var_5x5(x), 256, 256)
// x: (8, 64, 256, 256) fp32.
//
// Single-load streaming pipeline: one 64-lane wave owns one 32-output-row
// full-width strip; lane l owns columns 4l..4l+3. The last 6 x-rows live in a
// named-register ring (R0..R4, xn) shifted statically each iteration -> each
// x byte is loaded from global exactly ONCE per wave.
//   iter u: xn = row y0+u (prefetched 1 ahead);
//           var row a = y0-4+u from fresh 5-row sums of R1..R4,xn
//             (neighbor column-sum exchange via __shfl, one DS hop);
//           emit output row gy = y0+u-5 using R0 (== x row gy, static slot).
// Var rows go to a depth-8 LDS ring (reuse distance <= ~6). All row loads are
// clamped into [vymin, vymax+4] so the unique-row footprint stays 1.16x.

namespace {

constexpr int W = 256;
constexpr int STRIP = 32;
#define SC (251.0f / 255.0f)  // align_corners scale (h-1)/(H-1)

__device__ __forceinline__ float4 ldrow(const float* xi, int r, int lo, int hi,
                                        int c0) {
  r = r < lo ? lo : (r > hi ? hi : r);
  return *(const float4*)(xi + (size_t)r * W + c0);
}

__global__ __launch_bounds__(256, 4) void ssf_ring(const float* __restrict__ x,
                                                   float* __restrict__ out) {
  __shared__ float ring_all[4][8 * 256];  // depth-8 var ring per wave (8 KB)

  const int tid = threadIdx.x;
  const int lane = tid & 63;
  const int wv = tid >> 6;
  float* const ring = ring_all[wv];

  // XCD-chunked block swizzle (1024 blocks, 8 XCDs -> bijective).
  const int b = blockIdx.x;
  const int bs = (b & 7) * 128 + (b >> 3);
  const int sid = __builtin_amdgcn_readfirstlane(bs * 4 + wv);
  const int img = sid >> 3;                // 0..511
  const int y0 = (sid & 7) * STRIP;        // strip base output row

  const float* const xi = x + (size_t)img * (W * W);
  float* const oi = out + (size_t)img * (W * W);

  const int vymin = (y0 * 251) / 255;
  int vymax = ((y0 + STRIP - 1) * 251) / 255 + 1;
  if (vymax > 251) vymax = 251;
  const int hi = vymax + 4;  // last x row used (<= 255)

  const int c0 = lane * 4;

  // ---- Per-lane horizontal bilinear constants ----
  const int q0 = (int)floorf((float)c0 * SC);
  float wxv[4];
  bool selA[4], selB[4];
#pragma unroll
  for (int i = 0; i < 4; ++i) {
    float xs = (float)(c0 + i) * SC;
    float x0f = floorf(xs);
    int x0i = (int)x0f;
    wxv[i] = xs - x0f;
    selA[i] = (x0i - q0) == i;
    int x1i = x0i + 1;
    if (x1i > 251) x1i = 251;
    selB[i] = (x1i - q0) == (i + 1);
  }

  // ---- Preload register ring: rows y0-5..y0 (clamped to [vymin, hi]) ----
  float4 R0 = ldrow(xi, y0 - 5, vymin, hi, c0);
  float4 R1 = ldrow(xi, y0 - 4, vymin, hi, c0);
  float4 R2 = ldrow(xi, y0 - 3, vymin, hi, c0);
  float4 R3 = ldrow(xi, y0 - 2, vymin, hi, c0);
  float4 R4 = ldrow(xi, y0 - 1, vymin, hi, c0);
  float4 xn = ldrow(xi, y0, vymin, hi, c0);

  const int nsrc = (lane < 63) ? lane + 1 : 63;  // neighbor lane (63: junk)

  int cur = -1000;
  float vl[5] = {0.f, 0.f, 0.f, 0.f, 0.f};
  float vh[5] = {0.f, 0.f, 0.f, 0.f, 0.f};

  for (int u = 0; u <= 36; ++u) {  // fixed 37 iterations
    // Prefetch next x row (clamped; duplicates stay cache-hot, no new traffic).
    float4 xnn = ldrow(xi, y0 + u + 1, vymin, hi, c0);

    // ---- Var row a = y0-4+u (wave-uniform guard) ----
    const int a = y0 - 4 + u;
    if (a >= vymin && a <= vymax) {
      float r1[4] = {R1.x, R1.y, R1.z, R1.w};
      float r2[4] = {R2.x, R2.y, R2.z, R2.w};
      float r3[4] = {R3.x, R3.y, R3.z, R3.w};
      float r4[4] = {R4.x, R4.y, R4.z, R4.w};
      float r5[4] = {xn.x, xn.y, xn.z, xn.w};
      float s5[4], q5[4];
#pragma unroll
      for (int i = 0; i < 4; ++i) {
        s5[i] = ((r1[i] + r2[i]) + (r3[i] + r4[i])) + r5[i];
        q5[i] = fmaf(r1[i], r1[i],
                     fmaf(r2[i], r2[i],
                          fmaf(r3[i], r3[i], fmaf(r4[i], r4[i], r5[i] * r5[i]))));
      }
      // Neighbor exchange: next lane's 4 column sums (one DS hop via bpermute).
      float ns0 = __shfl(s5[0], nsrc, 64), ns1 = __shfl(s5[1], nsrc, 64);
      float ns2 = __shfl(s5[2], nsrc, 64), ns3 = __shfl(s5[3], nsrc, 64);
      float nq0 = __shfl(q5[0], nsrc, 64), nq1 = __shfl(q5[1], nsrc, 64);
      float nq2 = __shfl(q5[2], nsrc, 64), nq3 = __shfl(q5[3], nsrc, 64);
      // Horizontal 5-tap (sliding) + unbiased variance, var cols c0..c0+3.
      float hs0 = ((s5[0] + s5[1]) + (s5[2] + s5[3])) + ns0;
      float hq0 = ((q5[0] + q5[1]) + (q5[2] + q5[3])) + nq0;
      float hs1 = hs0 - s5[0] + ns1;
      float hq1 = hq0 - q5[0] + nq1;
      float hs2 = hs1 - s5[1] + ns2;
      float hq2 = hq1 - q5[1] + nq2;
      float hs3 = hs2 - s5[2] + ns3;
      float hq3 = hq2 - q5[2] + nq3;
      float4 vr4;
      vr4.x = (hq0 - hs0 * hs0 * (1.0f / 25.0f)) * (1.0f / 24.0f);
      vr4.y = (hq1 - hs1 * hs1 * (1.0f / 25.0f)) * (1.0f / 24.0f);
      vr4.z = (hq2 - hs2 * hs2 * (1.0f / 25.0f)) * (1.0f / 24.0f);
      vr4.w = (hq3 - hs3 * hs3 * (1.0f / 25.0f)) * (1.0f / 24.0f);
      *(float4*)(ring + (a & 7) * 256 + c0) = vr4;
    }

    // ---- Emit output row gy = y0+u-5 from R0 (wave-uniform guard) ----
    if (u >= 5) {
      const int gy = y0 + u - 5;
      const int vy = (gy * 251) / 255;  // exact integer floor
      int vy1 = vy + 1;
      if (vy1 > 251) vy1 = 251;
      float ys = (float)gy * SC;
      float wy = ys - (float)vy;
      if (vy != cur) {  // wave-uniform
        if (vy == cur + 1) {
#pragma unroll
          for (int i = 0; i < 5; ++i) vl[i] = vh[i];  // row-carry reuse
        } else {
          const float* rp = ring + (vy & 7) * 256 + q0;  // first emit only
#pragma unroll
          for (int i = 0; i < 5; ++i) vl[i] = rp[i];
        }
        if (vy1 == vy) {
#pragma unroll
          for (int i = 0; i < 5; ++i) vh[i] = vl[i];  // bottom clamp
        } else {
          const float* rp = ring + (vy1 & 7) * 256 + q0;
#pragma unroll
          for (int i = 0; i < 5; ++i) vh[i] = rp[i];
        }
        cur = vy;
      }
      float xa[4] = {R0.x, R0.y, R0.z, R0.w};
      float omwy = 1.0f - wy;
      float res[4];
#pragma unroll
      for (int i = 0; i < 4; ++i) {
        float a00 = (i == 0) ? vl[0] : (selA[i] ? vl[i] : vl[i - 1]);
        float a10 = (i == 0) ? vh[0] : (selA[i] ? vh[i] : vh[i - 1]);
        float a01 = selB[i] ? vl[i + 1] : vl[i];
        float a11 = selB[i] ? vh[i + 1] : vh[i];
        // Reference order: rows (wy) first, then cols (wx).
        float left = a00 * omwy + a10 * wy;
        float right = a01 * omwy + a11 * wy;
        res[i] = (left * (1.0f - wxv[i]) + right * wxv[i]) * xa[i];
      }
      *(float4*)(oi + (size_t)gy * W + c0) =
          make_float4(res[0], res[1], res[2], res[3]);
    }

    // ---- Static ring shift (named registers, no dynamic indexing) ----
    R0 = R1; R1 = R2; R2 = R3; R3 = R4; R4 = xn; xn = xnn;
  }
}

}  // namespace

extern "C" void kernel_launch(void* const* d_in, const int* in_sizes, int n_in,
                              void* d_out, int out_size, void* d_ws, size_t ws_size,
                              hipStream_t stream) {
  const float* x = (const float*)d_in[0];
  float* out = (float*)d_out;
  // 4096 strips (512 images x 8 strips), 4 waves (strips) per 256-thread block.
  ssf_ring<<<dim3(1024), dim3(256), 0, stream>>>(x, out);
}